// Round 6
// baseline (33.599 us; speedup 1.0000x reference)
//
#include <hip/hip_runtime.h>

typedef __attribute__((ext_vector_type(4))) float f32x4;
typedef __attribute__((ext_vector_type(8))) short s16x8;
typedef __attribute__((ext_vector_type(4))) int   i32x4;

constexpr int BATCH = 131072;
constexpr int T = 10;
constexpr int H = 32;

__device__ __forceinline__ unsigned cvt_pk_bf16(float a, float b) {
    unsigned d;
    asm("v_cvt_pk_bf16_f32 %0, %1, %2" : "=v"(d) : "v"(a), "v"(b));
    return d;   // lo16 = bf16(a), hi16 = bf16(b)
}

// 8 consecutive-k f32 -> bf16x8 hi fragment + bf16x8 lo (residual) fragment
__device__ __forceinline__ void pack_hilo8(const float (&v)[8], i32x4& hi, i32x4& lo) {
    #pragma unroll
    for (int p = 0; p < 4; ++p) {
        unsigned hb = cvt_pk_bf16(v[2*p], v[2*p+1]);
        float f0 = __builtin_bit_cast(float, hb << 16);
        float f1 = __builtin_bit_cast(float, hb & 0xFFFF0000u);
        hi[p] = (int)hb;
        lo[p] = (int)cvt_pk_bf16(v[2*p] - f0, v[2*p+1] - f1);
    }
}

__device__ __forceinline__ f32x4 mfma16(i32x4 a, i32x4 b, f32x4 c) {
    return __builtin_amdgcn_mfma_f32_16x16x32_bf16(
        __builtin_bit_cast(s16x8, a), __builtin_bit_cast(s16x8, b), c, 0, 0, 0);
}

__device__ __forceinline__ float fast_tanh(float v) {
    float e = __expf(2.0f * v);
    return 1.0f - 2.0f * __builtin_amdgcn_rcpf(e + 1.0f);
}

// a' = [a(0:31); b(0:31)], b' = [a(32:63); b(32:63)]
__device__ __forceinline__ void swap32(int& a, int& b) {
    asm("v_permlane32_swap_b32 %0, %1" : "+v"(a), "+v"(b));
}
// per 32-half: a' = [a(even16), b(even16)], b' = [a(odd16), b(odd16)]
__device__ __forceinline__ void swap16(int& a, int& b) {
    asm("v_permlane16_swap_b32 %0, %1" : "+v"(a), "+v"(b));
}

extern "C" __global__ void __launch_bounds__(256)
rnn_mfma(const float* __restrict__ x,      // [B, T]
         const float* __restrict__ h0,     // [B, H]
         const float* __restrict__ W_ih,   // [H]
         const float* __restrict__ W_hh,   // [H, H] row-major W_hh[j][k]
         const float* __restrict__ b_ih,   // [H]
         const float* __restrict__ b_hh,   // [H]
         const float* __restrict__ W_out,  // [H]
         const float* __restrict__ b_out,  // [1]
         float* __restrict__ out)          // outs [B*T] then hT [B*H]
{
    const int tid  = threadIdx.x;
    const int wave = tid >> 6;
    const int lane = tid & 63;
    const int nl   = lane & 15;            // D col = batch slot m
    const int g    = lane >> 4;
    const int b0   = blockIdx.x * 64 + wave * 16;
    const int m    = b0 + nl;              // this lane's batch row

    // A fragments of W_hh (constant): A[j][k]; tile0 j=nl, tile1 j=nl+16; k=8g..8g+7
    i32x4 a0h, a0l, a1h, a1l;
    {
        float v[8];
        const float4* p = reinterpret_cast<const float4*>(W_hh + nl * H + 8 * g);
        float4 u0 = p[0], u1 = p[1];
        v[0]=u0.x; v[1]=u0.y; v[2]=u0.z; v[3]=u0.w; v[4]=u1.x; v[5]=u1.y; v[6]=u1.z; v[7]=u1.w;
        pack_hilo8(v, a0h, a0l);
        const float4* q = reinterpret_cast<const float4*>(W_hh + (nl + 16) * H + 8 * g);
        float4 w0 = q[0], w1 = q[1];
        v[0]=w0.x; v[1]=w0.y; v[2]=w0.z; v[3]=w0.w; v[4]=w1.x; v[5]=w1.y; v[6]=w1.z; v[7]=w1.w;
        pack_hilo8(v, a1h, a1l);
    }

    // per-lane j-constants for D rows j = 4g+r (tile0) and 16+4g+r (tile1)
    float vb0[4], vw0[4], wo0[4], vb1[4], vw1[4], wo1[4];
    #pragma unroll
    for (int r = 0; r < 4; ++r) {
        const int j0 = 4 * g + r, j1 = j0 + 16;
        vb0[r] = b_ih[j0] + b_hh[j0]; vw0[r] = W_ih[j0]; wo0[r] = W_out[j0];
        vb1[r] = b_ih[j1] + b_hh[j1]; vw1[r] = W_ih[j1]; wo1[r] = W_out[j1];
    }
    const float bo = b_out[0];

    // initial B-frag (h^T): lane holds h0[m][k=8g..8g+7]
    i32x4 bh, bl;
    {
        float v[8];
        const float4* p = reinterpret_cast<const float4*>(h0 + (size_t)m * H + 8 * g);
        float4 u0 = p[0], u1 = p[1];
        v[0]=u0.x; v[1]=u0.y; v[2]=u0.z; v[3]=u0.w; v[4]=u1.x; v[5]=u1.y; v[6]=u1.z; v[7]=u1.w;
        pack_hilo8(v, bh, bl);
    }

    const float* xr   = x + (size_t)m * T;
    float*       orow = out + (size_t)m * T;

    float hc0[4], hc1[4];    // current h, D layout: row j=4g+r (+16), col m=nl
    float xm = xr[0];

    #pragma unroll 1
    for (int t = 0; t < T; ++t) {
        float xnext = (t + 1 < T) ? xr[t + 1] : 0.0f;

        // C init: bias[j] + x[m]*W_ih[j]  (pure f32; x never rounded)
        f32x4 d0, d1;
        #pragma unroll
        for (int r = 0; r < 4; ++r) {
            d0[r] = fmaf(xm, vw0[r], vb0[r]);
            d1[r] = fmaf(xm, vw1[r], vb1[r]);
        }

        // D = W_hh · h^T, split-bf16 (hi·hi + lo·hi + hi·lo)
        d0 = mfma16(a0h, bh, d0);
        d1 = mfma16(a1h, bh, d1);
        d0 = mfma16(a0l, bh, d0);
        d1 = mfma16(a1l, bh, d1);
        d0 = mfma16(a0h, bl, d0);
        d1 = mfma16(a1h, bl, d1);

        // tanh + output-projection partial (exact f32)
        float o = 0.0f;
        #pragma unroll
        for (int r = 0; r < 4; ++r) {
            hc0[r] = fast_tanh(d0[r]);
            hc1[r] = fast_tanh(d1[r]);
            o = fmaf(hc0[r], wo0[r], o);
            o = fmaf(hc1[r], wo1[r], o);
        }
        // reduce o across the 4 g-groups (same nl): halves, then 16-groups
        {
            int oa = __builtin_bit_cast(int, o), ob = oa;
            swap32(oa, ob);
            float s = __builtin_bit_cast(float, oa) + __builtin_bit_cast(float, ob);
            int sa = __builtin_bit_cast(int, s), sb = sa;
            swap16(sa, sb);
            o = __builtin_bit_cast(float, sa) + __builtin_bit_cast(float, sb) + bo;
        }
        if (g == 0) orow[t] = o;

        if (t + 1 < T) {
            // pack h to bf16 hi/lo pairs, then D->B transpose with 8 permlane swaps
            int w0 = (int)cvt_pk_bf16(hc0[0], hc0[1]);   // pair 2g
            int w1 = (int)cvt_pk_bf16(hc0[2], hc0[3]);   // pair 2g+1
            int w2 = (int)cvt_pk_bf16(hc1[0], hc1[1]);   // pair 8+2g
            int w3 = (int)cvt_pk_bf16(hc1[2], hc1[3]);   // pair 8+2g+1
            float q0 = hc0[0] - __builtin_bit_cast(float, (unsigned)w0 << 16);
            float q1 = hc0[1] - __builtin_bit_cast(float, (unsigned)w0 & 0xFFFF0000u);
            float q2 = hc0[2] - __builtin_bit_cast(float, (unsigned)w1 << 16);
            float q3 = hc0[3] - __builtin_bit_cast(float, (unsigned)w1 & 0xFFFF0000u);
            float q4 = hc1[0] - __builtin_bit_cast(float, (unsigned)w2 << 16);
            float q5 = hc1[1] - __builtin_bit_cast(float, (unsigned)w2 & 0xFFFF0000u);
            float q6 = hc1[2] - __builtin_bit_cast(float, (unsigned)w3 << 16);
            float q7 = hc1[3] - __builtin_bit_cast(float, (unsigned)w3 & 0xFFFF0000u);
            int l0 = (int)cvt_pk_bf16(q0, q1);
            int l1 = (int)cvt_pk_bf16(q2, q3);
            int l2 = (int)cvt_pk_bf16(q4, q5);
            int l3 = (int)cvt_pk_bf16(q6, q7);
            // pairs {2g,2g+1,8+2g,8+2g+1} -> {4g,4g+1,4g+2,4g+3} = k 8g..8g+7
            swap32(w0, w2); swap32(w1, w3);
            swap16(w0, w2); swap16(w1, w3);
            swap32(l0, l2); swap32(l1, l3);
            swap16(l0, l2); swap16(l1, l3);
            bh = (i32x4){w0, w1, w2, w3};
            bl = (i32x4){l0, l1, l2, l3};
        }
        xm = xnext;
    }

    // hT: h[m][j]; tile0 j=4g..4g+3, tile1 j=16+4g..16+4g+3 -> two float4 stores
    float* hb = out + (size_t)BATCH * T + (size_t)m * H;
    float4 s0, s1;
    s0.x = hc0[0]; s0.y = hc0[1]; s0.z = hc0[2]; s0.w = hc0[3];
    s1.x = hc1[0]; s1.y = hc1[1]; s1.z = hc1[2]; s1.w = hc1[3];
    *reinterpret_cast<float4*>(hb + 4 * g)      = s0;
    *reinterpret_cast<float4*>(hb + 16 + 4 * g) = s1;
}

extern "C" void kernel_launch(void* const* d_in, const int* in_sizes, int n_in,
                              void* d_out, int out_size, void* d_ws, size_t ws_size,
                              hipStream_t stream) {
    const float* x     = (const float*)d_in[0];
    const float* h0    = (const float*)d_in[1];
    const float* W_ih  = (const float*)d_in[2];
    const float* W_hh  = (const float*)d_in[3];
    const float* b_ih  = (const float*)d_in[4];
    const float* b_hh  = (const float*)d_in[5];
    const float* W_out = (const float*)d_in[6];
    const float* b_out = (const float*)d_in[7];
    float* out = (float*)d_out;

    rnn_mfma<<<BATCH / 64, 256, 0, stream>>>(
        x, h0, W_ih, W_hh, b_ih, b_hh, W_out, b_out, out);
}

// Round 9
// 32.546 us; speedup vs baseline: 1.0324x; 1.0324x over previous
//
#include <hip/hip_runtime.h>

typedef __attribute__((ext_vector_type(4))) float f32x4;
typedef __attribute__((ext_vector_type(8))) short s16x8;
typedef __attribute__((ext_vector_type(4))) int   i32x4;

constexpr int BATCH = 131072;
constexpr int T = 10;
constexpr int H = 32;

__device__ __forceinline__ unsigned cvt_pk_bf16(float a, float b) {
    unsigned d;
    asm("v_cvt_pk_bf16_f32 %0, %1, %2" : "=v"(d) : "v"(a), "v"(b));
    return d;   // lo16 = bf16(a), hi16 = bf16(b)
}

// 8 consecutive-k f32 -> bf16x8 hi fragment + bf16x8 lo (residual) fragment
__device__ __forceinline__ void pack_hilo8(const float (&v)[8], i32x4& hi, i32x4& lo) {
    #pragma unroll
    for (int p = 0; p < 4; ++p) {
        unsigned hb = cvt_pk_bf16(v[2*p], v[2*p+1]);
        float f0 = __builtin_bit_cast(float, hb << 16);
        float f1 = __builtin_bit_cast(float, hb & 0xFFFF0000u);
        hi[p] = (int)hb;
        lo[p] = (int)cvt_pk_bf16(v[2*p] - f0, v[2*p+1] - f1);
    }
}

__device__ __forceinline__ f32x4 mfma16(i32x4 a, i32x4 b, f32x4 c) {
    return __builtin_amdgcn_mfma_f32_16x16x32_bf16(
        __builtin_bit_cast(s16x8, a), __builtin_bit_cast(s16x8, b), c, 0, 0, 0);
}

__device__ __forceinline__ float fast_tanh(float v) {
    // tanh(v) = 1 - 2/(exp(2v)+1); overflow-safe at both ends
    float e = __expf(2.0f * v);
    return fmaf(-2.0f, __builtin_amdgcn_rcpf(e + 1.0f), 1.0f);
}

__device__ __forceinline__ void swap32(int& a, int& b) {
    asm("v_permlane32_swap_b32 %0, %1" : "+v"(a), "+v"(b));
}
__device__ __forceinline__ void swap16(int& a, int& b) {
    asm("v_permlane16_swap_b32 %0, %1" : "+v"(a), "+v"(b));
}

extern "C" __global__ void __launch_bounds__(256, 4)
rnn_mfma(const float* __restrict__ x,      // [B, T]
         const float* __restrict__ h0,     // [B, H]
         const float* __restrict__ W_ih,   // [H]
         const float* __restrict__ W_hh,   // [H, H] row-major W_hh[j][k]
         const float* __restrict__ b_ih,   // [H]
         const float* __restrict__ b_hh,   // [H]
         const float* __restrict__ W_out,  // [H]
         const float* __restrict__ b_out,  // [1]
         float* __restrict__ out)          // outs [B*T] then hT [B*H]
{
    const int tid  = threadIdx.x;
    const int wave = tid >> 6;
    const int lane = tid & 63;
    const int nl   = lane & 15;            // batch slot within a 16-row tile
    const int g    = lane >> 4;
    const int base = blockIdx.x * 128 + wave * 32;   // 2 tiles x 16 rows per wave
    const int m0   = base + nl;
    const int m1   = base + 16 + nl;

    // ---- A fragments of W_hh (constant): row j = nl (+16), k-octet 8g..8g+7 ----
    i32x4 a0h, a0l, a1h, a1l;
    {
        float v[8];
        const float4* p = reinterpret_cast<const float4*>(W_hh + nl * H + 8 * g);
        float4 u0 = p[0], u1 = p[1];
        v[0]=u0.x; v[1]=u0.y; v[2]=u0.z; v[3]=u0.w; v[4]=u1.x; v[5]=u1.y; v[6]=u1.z; v[7]=u1.w;
        pack_hilo8(v, a0h, a0l);
        const float4* q = reinterpret_cast<const float4*>(W_hh + (nl + 16) * H + 8 * g);
        float4 w0 = q[0], w1 = q[1];
        v[0]=w0.x; v[1]=w0.y; v[2]=w0.z; v[3]=w0.w; v[4]=w1.x; v[5]=w1.y; v[6]=w1.z; v[7]=w1.w;
        pack_hilo8(v, a1h, a1l);
    }

    // per-lane j-constants for D rows j = 4g+r (tile0) and 16+4g+r (tile1)
    float vb0[4], vw0[4], wo0[4], vb1[4], vw1[4], wo1[4];
    #pragma unroll
    for (int r = 0; r < 4; ++r) {
        const int j0 = 4 * g + r, j1 = j0 + 16;
        vb0[r] = b_ih[j0] + b_hh[j0]; vw0[r] = W_ih[j0]; wo0[r] = W_out[j0];
        vb1[r] = b_ih[j1] + b_hh[j1]; vw1[r] = W_ih[j1]; wo1[r] = W_out[j1];
    }
    const float bo = b_out[0];

    // ---- initial B fragments from h0: lane holds h0[m][k=8g..8g+7] ----
    i32x4 bh[2], bl[2];
    #pragma unroll
    for (int u = 0; u < 2; ++u) {
        float v[8];
        const int mu = (u == 0) ? m0 : m1;
        const float4* p = reinterpret_cast<const float4*>(h0 + (size_t)mu * H + 8 * g);
        float4 u0 = p[0], u1 = p[1];
        v[0]=u0.x; v[1]=u0.y; v[2]=u0.z; v[3]=u0.w; v[4]=u1.x; v[5]=u1.y; v[6]=u1.z; v[7]=u1.w;
        pack_hilo8(v, bh[u], bl[u]);
    }

    const float* xr0 = x + (size_t)m0 * T;
    const float* xr1 = x + (size_t)m1 * T;

    float hc0[2][4], hc1[2][4];
    float xt0 = xr0[0], xt1 = xr1[0];

    #pragma unroll 1
    for (int t = 0; t < T; ++t) {
        // prefetch next x (one ahead; same cache line most steps)
        float xn0 = (t + 1 < T) ? xr0[t + 1] : 0.0f;
        float xn1 = (t + 1 < T) ? xr1[t + 1] : 0.0f;

        // C init: bias[j] + x[m]*W_ih[j]  (pure f32; x never rounded)
        f32x4 d0[2], d1[2];
        #pragma unroll
        for (int r = 0; r < 4; ++r) {
            d0[0][r] = fmaf(xt0, vw0[r], vb0[r]);
            d1[0][r] = fmaf(xt0, vw1[r], vb1[r]);
            d0[1][r] = fmaf(xt1, vw0[r], vb0[r]);
            d1[1][r] = fmaf(xt1, vw1[r], vb1[r]);
        }

        // D = W_hh · h^T, split-bf16; two independent chains (u) interleaved
        #pragma unroll
        for (int u = 0; u < 2; ++u) { d0[u] = mfma16(a0h, bh[u], d0[u]);
                                      d1[u] = mfma16(a1h, bh[u], d1[u]); }
        #pragma unroll
        for (int u = 0; u < 2; ++u) { d0[u] = mfma16(a0l, bh[u], d0[u]);
                                      d1[u] = mfma16(a1l, bh[u], d1[u]); }
        #pragma unroll
        for (int u = 0; u < 2; ++u) { d0[u] = mfma16(a0h, bl[u], d0[u]);
                                      d1[u] = mfma16(a1h, bl[u], d1[u]); }

        #pragma unroll
        for (int u = 0; u < 2; ++u) {
            // tanh + output-projection partial (exact f32)
            float o = 0.0f;
            #pragma unroll
            for (int r = 0; r < 4; ++r) {
                hc0[u][r] = fast_tanh(d0[u][r]);
                hc1[u][r] = fast_tanh(d1[u][r]);
                o = fmaf(hc0[u][r], wo0[r], o);
                o = fmaf(hc1[u][r], wo1[r], o);
            }
            // reduce o across the 4 g-groups (same nl) — safe cross-lane intrinsics
            o += __shfl_xor(o, 32);
            o += __shfl_xor(o, 16);
            if (g == 0) out[(size_t)(base + u * 16 + nl) * T + t] = o + bo;

            if (t + 1 < T) {
                // D -> B repack: bf16 pack + 8 permlane swaps (proven R6 path)
                int w0 = (int)cvt_pk_bf16(hc0[u][0], hc0[u][1]);   // pair 2g
                int w1 = (int)cvt_pk_bf16(hc0[u][2], hc0[u][3]);   // pair 2g+1
                int w2 = (int)cvt_pk_bf16(hc1[u][0], hc1[u][1]);   // pair 8+2g
                int w3 = (int)cvt_pk_bf16(hc1[u][2], hc1[u][3]);   // pair 8+2g+1
                float q0 = hc0[u][0] - __builtin_bit_cast(float, (unsigned)w0 << 16);
                float q1 = hc0[u][1] - __builtin_bit_cast(float, (unsigned)w0 & 0xFFFF0000u);
                float q2 = hc0[u][2] - __builtin_bit_cast(float, (unsigned)w1 << 16);
                float q3 = hc0[u][3] - __builtin_bit_cast(float, (unsigned)w1 & 0xFFFF0000u);
                float q4 = hc1[u][0] - __builtin_bit_cast(float, (unsigned)w2 << 16);
                float q5 = hc1[u][1] - __builtin_bit_cast(float, (unsigned)w2 & 0xFFFF0000u);
                float q6 = hc1[u][2] - __builtin_bit_cast(float, (unsigned)w3 << 16);
                float q7 = hc1[u][3] - __builtin_bit_cast(float, (unsigned)w3 & 0xFFFF0000u);
                int l0 = (int)cvt_pk_bf16(q0, q1);
                int l1 = (int)cvt_pk_bf16(q2, q3);
                int l2 = (int)cvt_pk_bf16(q4, q5);
                int l3 = (int)cvt_pk_bf16(q6, q7);
                // pairs {2g,2g+1,8+2g,8+2g+1} -> {4g..4g+3} = k 8g..8g+7
                swap32(w0, w2); swap32(w1, w3);
                swap16(w0, w2); swap16(w1, w3);
                swap32(l0, l2); swap32(l1, l3);
                swap16(l0, l2); swap16(l1, l3);
                bh[u] = (i32x4){w0, w1, w2, w3};
                bl[u] = (i32x4){l0, l1, l2, l3};
            }
        }
        xt0 = xn0;
        xt1 = xn1;
    }

    // hT: h[m][j]; tile0 j=4g..4g+3, tile1 j=16+4g..16+4g+3 per batch tile
    #pragma unroll
    for (int u = 0; u < 2; ++u) {
        float* hb = out + (size_t)BATCH * T + (size_t)(base + u * 16 + nl) * H;
        float4 s0, s1;
        s0.x = hc0[u][0]; s0.y = hc0[u][1]; s0.z = hc0[u][2]; s0.w = hc0[u][3];
        s1.x = hc1[u][0]; s1.y = hc1[u][1]; s1.z = hc1[u][2]; s1.w = hc1[u][3];
        *reinterpret_cast<float4*>(hb + 4 * g)      = s0;
        *reinterpret_cast<float4*>(hb + 16 + 4 * g) = s1;
    }
}

extern "C" void kernel_launch(void* const* d_in, const int* in_sizes, int n_in,
                              void* d_out, int out_size, void* d_ws, size_t ws_size,
                              hipStream_t stream) {
    const float* x     = (const float*)d_in[0];
    const float* h0    = (const float*)d_in[1];
    const float* W_ih  = (const float*)d_in[2];
    const float* W_hh  = (const float*)d_in[3];
    const float* b_ih  = (const float*)d_in[4];
    const float* b_hh  = (const float*)d_in[5];
    const float* W_out = (const float*)d_in[6];
    const float* b_out = (const float*)d_in[7];
    float* out = (float*)d_out;

    rnn_mfma<<<BATCH / 128, 256, 0, stream>>>(
        x, h0, W_ih, W_hh, b_ih, b_hh, W_out, b_out, out);
}

// Round 10
// 29.864 us; speedup vs baseline: 1.1251x; 1.0898x over previous
//
#include <hip/hip_runtime.h>

typedef __attribute__((ext_vector_type(4))) float f32x4;
typedef __attribute__((ext_vector_type(8))) short s16x8;
typedef __attribute__((ext_vector_type(4))) int   i32x4;

constexpr int BATCH = 131072;
constexpr int T = 10;
constexpr int H = 32;

__device__ __forceinline__ unsigned cvt_pk_bf16(float a, float b) {
    unsigned d;
    asm("v_cvt_pk_bf16_f32 %0, %1, %2" : "=v"(d) : "v"(a), "v"(b));
    return d;   // lo16 = bf16(a), hi16 = bf16(b)
}

// 8 f32 (in fragment k-order) -> bf16x8 hi fragment + lo (residual) fragment
__device__ __forceinline__ void pack_hilo8(const float (&v)[8], i32x4& hi, i32x4& lo) {
    #pragma unroll
    for (int p = 0; p < 4; ++p) {
        unsigned hb = cvt_pk_bf16(v[2*p], v[2*p+1]);
        float f0 = __builtin_bit_cast(float, hb << 16);
        float f1 = __builtin_bit_cast(float, hb & 0xFFFF0000u);
        hi[p] = (int)hb;
        lo[p] = (int)cvt_pk_bf16(v[2*p] - f0, v[2*p+1] - f1);
    }
}

__device__ __forceinline__ f32x4 mfma16(i32x4 a, i32x4 b, f32x4 c) {
    return __builtin_amdgcn_mfma_f32_16x16x32_bf16(
        __builtin_bit_cast(s16x8, a), __builtin_bit_cast(s16x8, b), c, 0, 0, 0);
}

__device__ __forceinline__ float fast_tanh(float v) {
    // tanh(v) = 1 - 2/(exp(2v)+1); overflow-safe at both ends
    float e = __expf(2.0f * v);
    return fmaf(-2.0f, __builtin_amdgcn_rcpf(e + 1.0f), 1.0f);
}

// sigma(8g+r') = 4g+r' (r'<4), 16+4g+(r'-4) (r'>=4).
// A'[j][k'] = W_hh[j][sigma(k')], B'[k'][m] = h[m][sigma(k')].
// With A' precomputed, the D-tile of step t (rows j=4g+r / 16+4g+r, col m=nl)
// packs DIRECTLY into step t+1's B-fragment: 4 cvt_pk per tile, zero
// cross-lane ops in the recurrence.

extern "C" __global__ void __launch_bounds__(256, 4)
rnn_mfma(const float* __restrict__ x,      // [B, T]
         const float* __restrict__ h0,     // [B, H]
         const float* __restrict__ W_ih,   // [H]
         const float* __restrict__ W_hh,   // [H, H] row-major W_hh[j][k]
         const float* __restrict__ b_ih,   // [H]
         const float* __restrict__ b_hh,   // [H]
         const float* __restrict__ W_out,  // [H]
         const float* __restrict__ b_out,  // [1]
         float* __restrict__ out)          // outs [B*T] then hT [B*H]
{
    const int tid  = threadIdx.x;
    const int wave = tid >> 6;
    const int lane = tid & 63;
    const int nl   = lane & 15;            // batch slot within a 16-row tile
    const int g    = lane >> 4;
    const int base = blockIdx.x * 128 + wave * 32;   // 2 tiles x 16 rows per wave
    const int m0   = base + nl;
    const int m1   = base + 16 + nl;

    // ---- A' fragments of W_hh (constant, sigma-permuted k') ----
    // lane (nl,g): rows j=nl (tile0), nl+16 (tile1); k' octet -> W cols
    // 4g..4g+3 then 16+4g..16+4g+3
    i32x4 a0h, a0l, a1h, a1l;
    {
        float v[8];
        const float* r0 = W_hh + nl * H;
        float4 u0 = *reinterpret_cast<const float4*>(r0 + 4 * g);
        float4 u1 = *reinterpret_cast<const float4*>(r0 + 16 + 4 * g);
        v[0]=u0.x; v[1]=u0.y; v[2]=u0.z; v[3]=u0.w;
        v[4]=u1.x; v[5]=u1.y; v[6]=u1.z; v[7]=u1.w;
        pack_hilo8(v, a0h, a0l);
        const float* r1 = W_hh + (nl + 16) * H;
        float4 w0 = *reinterpret_cast<const float4*>(r1 + 4 * g);
        float4 w1 = *reinterpret_cast<const float4*>(r1 + 16 + 4 * g);
        v[0]=w0.x; v[1]=w0.y; v[2]=w0.z; v[3]=w0.w;
        v[4]=w1.x; v[5]=w1.y; v[6]=w1.z; v[7]=w1.w;
        pack_hilo8(v, a1h, a1l);
    }

    // per-lane j-constants for D rows j = 4g+r (tile0) and 16+4g+r (tile1)
    float vb0[4], vw0[4], wo0[4], vb1[4], vw1[4], wo1[4];
    #pragma unroll
    for (int r = 0; r < 4; ++r) {
        const int j0 = 4 * g + r, j1 = j0 + 16;
        vb0[r] = b_ih[j0] + b_hh[j0]; vw0[r] = W_ih[j0]; wo0[r] = W_out[j0];
        vb1[r] = b_ih[j1] + b_hh[j1]; vw1[r] = W_ih[j1]; wo1[r] = W_out[j1];
    }
    const float bo = b_out[0];

    // ---- initial B' fragments from h0 (sigma-permuted columns) ----
    i32x4 bh[2], bl[2];
    #pragma unroll
    for (int u = 0; u < 2; ++u) {
        float v[8];
        const float* hr = h0 + (size_t)((u == 0) ? m0 : m1) * H;
        float4 u0 = *reinterpret_cast<const float4*>(hr + 4 * g);
        float4 u1 = *reinterpret_cast<const float4*>(hr + 16 + 4 * g);
        v[0]=u0.x; v[1]=u0.y; v[2]=u0.z; v[3]=u0.w;
        v[4]=u1.x; v[5]=u1.y; v[6]=u1.z; v[7]=u1.w;
        pack_hilo8(v, bh[u], bl[u]);
    }

    const float* xr0 = x + (size_t)m0 * T;
    const float* xr1 = x + (size_t)m1 * T;

    float hc0[2][4], hc1[2][4];
    float xt0 = xr0[0], xt1 = xr1[0];

    #pragma unroll 1
    for (int t = 0; t < T; ++t) {
        // prefetch next x (one ahead; lines already in L1 after t=0 gather)
        float xn0 = (t + 1 < T) ? xr0[t + 1] : 0.0f;
        float xn1 = (t + 1 < T) ? xr1[t + 1] : 0.0f;

        // C init: bias[j] + x[m]*W_ih[j]  (pure f32; x never rounded)
        f32x4 d0[2], d1[2];
        #pragma unroll
        for (int r = 0; r < 4; ++r) {
            d0[0][r] = fmaf(xt0, vw0[r], vb0[r]);
            d1[0][r] = fmaf(xt0, vw1[r], vb1[r]);
            d0[1][r] = fmaf(xt1, vw0[r], vb0[r]);
            d1[1][r] = fmaf(xt1, vw1[r], vb1[r]);
        }

        // D = W'·h^T, split-bf16; two independent chains (u) interleaved
        #pragma unroll
        for (int u = 0; u < 2; ++u) { d0[u] = mfma16(a0h, bh[u], d0[u]);
                                      d1[u] = mfma16(a1h, bh[u], d1[u]); }
        #pragma unroll
        for (int u = 0; u < 2; ++u) { d0[u] = mfma16(a0l, bh[u], d0[u]);
                                      d1[u] = mfma16(a1l, bh[u], d1[u]); }
        #pragma unroll
        for (int u = 0; u < 2; ++u) { d0[u] = mfma16(a0h, bl[u], d0[u]);
                                      d1[u] = mfma16(a1h, bl[u], d1[u]); }

        #pragma unroll
        for (int u = 0; u < 2; ++u) {
            // tanh + output-projection partial (exact f32)
            float o = 0.0f;
            #pragma unroll
            for (int r = 0; r < 4; ++r) {
                hc0[u][r] = fast_tanh(d0[u][r]);
                hc1[u][r] = fast_tanh(d1[u][r]);
                o = fmaf(hc0[u][r], wo0[r], o);
                o = fmaf(hc1[u][r], wo1[r], o);
            }
            // reduce o across the 4 g-groups (same nl) — safe cross-lane intrinsics
            o += __shfl_xor(o, 32);
            o += __shfl_xor(o, 16);
            if (g == 0) out[(size_t)(base + u * 16 + nl) * T + t] = o + bo;

            if (t + 1 < T) {
                // D -> B': direct per-lane pack in k'-order, zero cross-lane ops
                unsigned p0 = cvt_pk_bf16(hc0[u][0], hc0[u][1]);
                unsigned p1 = cvt_pk_bf16(hc0[u][2], hc0[u][3]);
                unsigned p2 = cvt_pk_bf16(hc1[u][0], hc1[u][1]);
                unsigned p3 = cvt_pk_bf16(hc1[u][2], hc1[u][3]);
                bh[u] = (i32x4){(int)p0, (int)p1, (int)p2, (int)p3};
                float q0 = hc0[u][0] - __builtin_bit_cast(float, p0 << 16);
                float q1 = hc0[u][1] - __builtin_bit_cast(float, p0 & 0xFFFF0000u);
                float q2 = hc0[u][2] - __builtin_bit_cast(float, p1 << 16);
                float q3 = hc0[u][3] - __builtin_bit_cast(float, p1 & 0xFFFF0000u);
                float q4 = hc1[u][0] - __builtin_bit_cast(float, p2 << 16);
                float q5 = hc1[u][1] - __builtin_bit_cast(float, p2 & 0xFFFF0000u);
                float q6 = hc1[u][2] - __builtin_bit_cast(float, p3 << 16);
                float q7 = hc1[u][3] - __builtin_bit_cast(float, p3 & 0xFFFF0000u);
                bl[u] = (i32x4){(int)cvt_pk_bf16(q0, q1), (int)cvt_pk_bf16(q2, q3),
                                (int)cvt_pk_bf16(q4, q5), (int)cvt_pk_bf16(q6, q7)};
            }
        }
        xt0 = xn0;
        xt1 = xn1;
    }

    // hT: h[m][j]; hc0 rows j=4g..4g+3, hc1 rows 16+4g..16+4g+3 per batch tile
    #pragma unroll
    for (int u = 0; u < 2; ++u) {
        float* hb = out + (size_t)BATCH * T + (size_t)(base + u * 16 + nl) * H;
        float4 s0, s1;
        s0.x = hc0[u][0]; s0.y = hc0[u][1]; s0.z = hc0[u][2]; s0.w = hc0[u][3];
        s1.x = hc1[u][0]; s1.y = hc1[u][1]; s1.z = hc1[u][2]; s1.w = hc1[u][3];
        *reinterpret_cast<float4*>(hb + 4 * g)      = s0;
        *reinterpret_cast<float4*>(hb + 16 + 4 * g) = s1;
    }
}

extern "C" void kernel_launch(void* const* d_in, const int* in_sizes, int n_in,
                              void* d_out, int out_size, void* d_ws, size_t ws_size,
                              hipStream_t stream) {
    const float* x     = (const float*)d_in[0];
    const float* h0    = (const float*)d_in[1];
    const float* W_ih  = (const float*)d_in[2];
    const float* W_hh  = (const float*)d_in[3];
    const float* b_ih  = (const float*)d_in[4];
    const float* b_hh  = (const float*)d_in[5];
    const float* W_out = (const float*)d_in[6];
    const float* b_out = (const float*)d_in[7];
    float* out = (float*)d_out;

    rnn_mfma<<<BATCH / 128, 256, 0, stream>>>(
        x, h0, W_ih, W_hh, b_ih, b_hh, W_out, b_out, out);
}

// Round 11
// 27.921 us; speedup vs baseline: 1.2034x; 1.0696x over previous
//
#include <hip/hip_runtime.h>

typedef __attribute__((ext_vector_type(4))) float f32x4;
typedef __attribute__((ext_vector_type(8))) short s16x8;
typedef __attribute__((ext_vector_type(4))) int   i32x4;

constexpr int BATCH = 131072;
constexpr int T = 10;
constexpr int H = 32;

__device__ __forceinline__ unsigned cvt_pk_bf16(float a, float b) {
    unsigned d;
    asm("v_cvt_pk_bf16_f32 %0, %1, %2" : "=v"(d) : "v"(a), "v"(b));
    return d;   // lo16 = bf16(a), hi16 = bf16(b)
}

// 8 f32 (in fragment k-order) -> bf16x8 hi fragment + lo (residual) fragment
__device__ __forceinline__ void pack_hilo8(const float (&v)[8], i32x4& hi, i32x4& lo) {
    #pragma unroll
    for (int p = 0; p < 4; ++p) {
        unsigned hb = cvt_pk_bf16(v[2*p], v[2*p+1]);
        float f0 = __builtin_bit_cast(float, hb << 16);
        float f1 = __builtin_bit_cast(float, hb & 0xFFFF0000u);
        hi[p] = (int)hb;
        lo[p] = (int)cvt_pk_bf16(v[2*p] - f0, v[2*p+1] - f1);
    }
}

// hi-only pack (B-side: h residual dropped by design)
__device__ __forceinline__ i32x4 pack_hi8(const float (&v)[8]) {
    i32x4 hi;
    #pragma unroll
    for (int p = 0; p < 4; ++p)
        hi[p] = (int)cvt_pk_bf16(v[2*p], v[2*p+1]);
    return hi;
}

__device__ __forceinline__ f32x4 mfma16(i32x4 a, i32x4 b, f32x4 c) {
    return __builtin_amdgcn_mfma_f32_16x16x32_bf16(
        __builtin_bit_cast(s16x8, a), __builtin_bit_cast(s16x8, b), c, 0, 0, 0);
}

__device__ __forceinline__ float fast_tanh(float v) {
    // tanh(v) = 1 - 2/(exp(2v)+1); overflow-safe at both ends
    float e = __expf(2.0f * v);
    return fmaf(-2.0f, __builtin_amdgcn_rcpf(e + 1.0f), 1.0f);
}

// sigma(8g+r') = 4g+r' (r'<4), 16+4g+(r'-4) (r'>=4).
// A'[j][k'] = W_hh[j][sigma(k')], B'[k'][m] = h[m][sigma(k')].
// With A' precomputed, the D-tile of step t (rows j=4g+r / 16+4g+r, col m=nl)
// packs DIRECTLY into step t+1's B-fragment: 4 cvt_pk per tile, zero
// cross-lane ops in the recurrence.
// Split precision: D = (A_hi + A_lo) · B_hi  — W is fp32-accurate (residual
// fragments are precomputed constants), h carries one bf16 rounding (2^-9),
// well inside the 2^-6 threshold.

extern "C" __global__ void __launch_bounds__(256, 4)
rnn_mfma(const float* __restrict__ x,      // [B, T]
         const float* __restrict__ h0,     // [B, H]
         const float* __restrict__ W_ih,   // [H]
         const float* __restrict__ W_hh,   // [H, H] row-major W_hh[j][k]
         const float* __restrict__ b_ih,   // [H]
         const float* __restrict__ b_hh,   // [H]
         const float* __restrict__ W_out,  // [H]
         const float* __restrict__ b_out,  // [1]
         float* __restrict__ out)          // outs [B*T] then hT [B*H]
{
    const int tid  = threadIdx.x;
    const int wave = tid >> 6;
    const int lane = tid & 63;
    const int nl   = lane & 15;            // batch slot within a 16-row tile
    const int g    = lane >> 4;
    const int base = blockIdx.x * 128 + wave * 32;   // 2 tiles x 16 rows per wave
    const int m0   = base + nl;
    const int m1   = base + 16 + nl;

    // ---- A' fragments of W_hh (constant, sigma-permuted k') ----
    i32x4 a0h, a0l, a1h, a1l;
    {
        float v[8];
        const float* r0 = W_hh + nl * H;
        float4 u0 = *reinterpret_cast<const float4*>(r0 + 4 * g);
        float4 u1 = *reinterpret_cast<const float4*>(r0 + 16 + 4 * g);
        v[0]=u0.x; v[1]=u0.y; v[2]=u0.z; v[3]=u0.w;
        v[4]=u1.x; v[5]=u1.y; v[6]=u1.z; v[7]=u1.w;
        pack_hilo8(v, a0h, a0l);
        const float* r1 = W_hh + (nl + 16) * H;
        float4 w0 = *reinterpret_cast<const float4*>(r1 + 4 * g);
        float4 w1 = *reinterpret_cast<const float4*>(r1 + 16 + 4 * g);
        v[0]=w0.x; v[1]=w0.y; v[2]=w0.z; v[3]=w0.w;
        v[4]=w1.x; v[5]=w1.y; v[6]=w1.z; v[7]=w1.w;
        pack_hilo8(v, a1h, a1l);
    }

    // per-lane j-constants for D rows j = 4g+r (tile0) and 16+4g+r (tile1)
    float vb0[4], vw0[4], wo0[4], vb1[4], vw1[4], wo1[4];
    #pragma unroll
    for (int r = 0; r < 4; ++r) {
        const int j0 = 4 * g + r, j1 = j0 + 16;
        vb0[r] = b_ih[j0] + b_hh[j0]; vw0[r] = W_ih[j0]; wo0[r] = W_out[j0];
        vb1[r] = b_ih[j1] + b_hh[j1]; vw1[r] = W_ih[j1]; wo1[r] = W_out[j1];
    }
    const float bo = b_out[0];

    // ---- initial B' fragments from h0 (sigma-permuted columns, hi-only) ----
    i32x4 bh[2];
    #pragma unroll
    for (int u = 0; u < 2; ++u) {
        float v[8];
        const float* hr = h0 + (size_t)((u == 0) ? m0 : m1) * H;
        float4 u0 = *reinterpret_cast<const float4*>(hr + 4 * g);
        float4 u1 = *reinterpret_cast<const float4*>(hr + 16 + 4 * g);
        v[0]=u0.x; v[1]=u0.y; v[2]=u0.z; v[3]=u0.w;
        v[4]=u1.x; v[5]=u1.y; v[6]=u1.z; v[7]=u1.w;
        bh[u] = pack_hi8(v);
    }

    const float* xr0 = x + (size_t)m0 * T;
    const float* xr1 = x + (size_t)m1 * T;

    float hc0[2][4], hc1[2][4];
    float xt0 = xr0[0], xt1 = xr1[0];

    #pragma unroll 1
    for (int t = 0; t < T; ++t) {
        // prefetch next x (one ahead; lines already cached after t=0)
        float xn0 = (t + 1 < T) ? xr0[t + 1] : 0.0f;
        float xn1 = (t + 1 < T) ? xr1[t + 1] : 0.0f;

        // C init: bias[j] + x[m]*W_ih[j]  (pure f32; x never rounded)
        f32x4 d0[2], d1[2];
        #pragma unroll
        for (int r = 0; r < 4; ++r) {
            d0[0][r] = fmaf(xt0, vw0[r], vb0[r]);
            d1[0][r] = fmaf(xt0, vw1[r], vb1[r]);
            d0[1][r] = fmaf(xt1, vw0[r], vb0[r]);
            d1[1][r] = fmaf(xt1, vw1[r], vb1[r]);
        }

        // D = (W_hi + W_lo) · h_hi^T ; two independent chains (u) interleaved
        #pragma unroll
        for (int u = 0; u < 2; ++u) { d0[u] = mfma16(a0h, bh[u], d0[u]);
                                      d1[u] = mfma16(a1h, bh[u], d1[u]); }
        #pragma unroll
        for (int u = 0; u < 2; ++u) { d0[u] = mfma16(a0l, bh[u], d0[u]);
                                      d1[u] = mfma16(a1l, bh[u], d1[u]); }

        #pragma unroll
        for (int u = 0; u < 2; ++u) {
            // tanh + output-projection partial (exact f32)
            float o = 0.0f;
            #pragma unroll
            for (int r = 0; r < 4; ++r) {
                hc0[u][r] = fast_tanh(d0[u][r]);
                hc1[u][r] = fast_tanh(d1[u][r]);
                o = fmaf(hc0[u][r], wo0[r], o);
                o = fmaf(hc1[u][r], wo1[r], o);
            }
            // reduce o across the 4 g-groups (same nl)
            o += __shfl_xor(o, 32);
            o += __shfl_xor(o, 16);
            if (g == 0) out[(size_t)(base + u * 16 + nl) * T + t] = o + bo;

            if (t + 1 < T) {
                // D -> B': direct per-lane hi pack in k'-order (4 cvt_pk)
                bh[u] = (i32x4){(int)cvt_pk_bf16(hc0[u][0], hc0[u][1]),
                                (int)cvt_pk_bf16(hc0[u][2], hc0[u][3]),
                                (int)cvt_pk_bf16(hc1[u][0], hc1[u][1]),
                                (int)cvt_pk_bf16(hc1[u][2], hc1[u][3])};
            }
        }
        xt0 = xn0;
        xt1 = xn1;
    }

    // hT: h[m][j]; hc0 rows j=4g..4g+3, hc1 rows 16+4g..16+4g+3 per batch tile
    #pragma unroll
    for (int u = 0; u < 2; ++u) {
        float* hb = out + (size_t)BATCH * T + (size_t)(base + u * 16 + nl) * H;
        float4 s0, s1;
        s0.x = hc0[u][0]; s0.y = hc0[u][1]; s0.z = hc0[u][2]; s0.w = hc0[u][3];
        s1.x = hc1[u][0]; s1.y = hc1[u][1]; s1.z = hc1[u][2]; s1.w = hc1[u][3];
        *reinterpret_cast<float4*>(hb + 4 * g)      = s0;
        *reinterpret_cast<float4*>(hb + 16 + 4 * g) = s1;
    }
}

extern "C" void kernel_launch(void* const* d_in, const int* in_sizes, int n_in,
                              void* d_out, int out_size, void* d_ws, size_t ws_size,
                              hipStream_t stream) {
    const float* x     = (const float*)d_in[0];
    const float* h0    = (const float*)d_in[1];
    const float* W_ih  = (const float*)d_in[2];
    const float* W_hh  = (const float*)d_in[3];
    const float* b_ih  = (const float*)d_in[4];
    const float* b_hh  = (const float*)d_in[5];
    const float* W_out = (const float*)d_in[6];
    const float* b_out = (const float*)d_in[7];
    float* out = (float*)d_out;

    rnn_mfma<<<BATCH / 128, 256, 0, stream>>>(
        x, h0, W_ih, W_hh, b_ih, b_hh, W_out, b_out, out);
}

// Round 12
// 27.073 us; speedup vs baseline: 1.2410x; 1.0313x over previous
//
#include <hip/hip_runtime.h>

typedef __attribute__((ext_vector_type(4))) float f32x4;
typedef __attribute__((ext_vector_type(8))) short s16x8;
typedef __attribute__((ext_vector_type(4))) int   i32x4;

constexpr int BATCH = 131072;
constexpr int T = 10;
constexpr int H = 32;

__device__ __forceinline__ unsigned cvt_pk_bf16(float a, float b) {
    unsigned d;
    asm("v_cvt_pk_bf16_f32 %0, %1, %2" : "=v"(d) : "v"(a), "v"(b));
    return d;   // lo16 = bf16(a), hi16 = bf16(b)
}

// 8 f32 (in fragment k-order) -> bf16x8 hi fragment + lo (residual) fragment
__device__ __forceinline__ void pack_hilo8(const float (&v)[8], i32x4& hi, i32x4& lo) {
    #pragma unroll
    for (int p = 0; p < 4; ++p) {
        unsigned hb = cvt_pk_bf16(v[2*p], v[2*p+1]);
        float f0 = __builtin_bit_cast(float, hb << 16);
        float f1 = __builtin_bit_cast(float, hb & 0xFFFF0000u);
        hi[p] = (int)hb;
        lo[p] = (int)cvt_pk_bf16(v[2*p] - f0, v[2*p+1] - f1);
    }
}

// hi-only pack
__device__ __forceinline__ i32x4 pack_hi8(const float (&v)[8]) {
    i32x4 hi;
    #pragma unroll
    for (int p = 0; p < 4; ++p)
        hi[p] = (int)cvt_pk_bf16(v[2*p], v[2*p+1]);
    return hi;
}

__device__ __forceinline__ f32x4 mfma16(i32x4 a, i32x4 b, f32x4 c) {
    return __builtin_amdgcn_mfma_f32_16x16x32_bf16(
        __builtin_bit_cast(s16x8, a), __builtin_bit_cast(s16x8, b), c, 0, 0, 0);
}

__device__ __forceinline__ float fast_tanh(float v) {
    // tanh(v) = 1 - 2/(exp(2v)+1); overflow-safe at both ends
    float e = __expf(2.0f * v);
    return fmaf(-2.0f, __builtin_amdgcn_rcpf(e + 1.0f), 1.0f);
}

// sigma(8g+r') = 4g+r' (r'<4), 16+4g+(r'-4) (r'>=4).
// A'[j][k'] = W_hh[j][sigma(k')], B'[k'][m] = h[m][sigma(k')].
// D-tile of step t packs directly into step t+1's B-fragment (4 cvt_pk),
// zero cross-lane ops anywhere in the loop.
// Output projection rides the MFMA pipe: aout row0 = W_out[sigma(k')],
// rows 1..15 zero -> D[0][m] = W_out . h_new for column m.

extern "C" __global__ void __launch_bounds__(256, 8)
rnn_mfma(const float* __restrict__ x,      // [B, T]
         const float* __restrict__ h0,     // [B, H]
         const float* __restrict__ W_ih,   // [H]
         const float* __restrict__ W_hh,   // [H, H] row-major W_hh[j][k]
         const float* __restrict__ b_ih,   // [H]
         const float* __restrict__ b_hh,   // [H]
         const float* __restrict__ W_out,  // [H]
         const float* __restrict__ b_out,  // [1]
         float* __restrict__ out)          // outs [B*T] then hT [B*H]
{
    const int tid  = threadIdx.x;
    const int wave = tid >> 6;
    const int lane = tid & 63;
    const int nl   = lane & 15;            // batch slot m / D col
    const int g    = lane >> 4;
    const int m    = blockIdx.x * 64 + wave * 16 + nl;

    // ---- A' fragments of W_hh (constant, sigma-permuted k') ----
    i32x4 a0h, a0l, a1h, a1l;
    {
        float v[8];
        const float* r0 = W_hh + nl * H;
        float4 u0 = *reinterpret_cast<const float4*>(r0 + 4 * g);
        float4 u1 = *reinterpret_cast<const float4*>(r0 + 16 + 4 * g);
        v[0]=u0.x; v[1]=u0.y; v[2]=u0.z; v[3]=u0.w;
        v[4]=u1.x; v[5]=u1.y; v[6]=u1.z; v[7]=u1.w;
        pack_hilo8(v, a0h, a0l);
        const float* r1 = W_hh + (nl + 16) * H;
        float4 w0 = *reinterpret_cast<const float4*>(r1 + 4 * g);
        float4 w1 = *reinterpret_cast<const float4*>(r1 + 16 + 4 * g);
        v[0]=w0.x; v[1]=w0.y; v[2]=w0.z; v[3]=w0.w;
        v[4]=w1.x; v[5]=w1.y; v[6]=w1.z; v[7]=w1.w;
        pack_hilo8(v, a1h, a1l);
    }

    // ---- aout: A row0 = W_out[sigma(k')], other rows zero ----
    i32x4 aout;
    {
        float v[8];
        float4 u0 = *reinterpret_cast<const float4*>(W_out + 4 * g);
        float4 u1 = *reinterpret_cast<const float4*>(W_out + 16 + 4 * g);
        v[0]=u0.x; v[1]=u0.y; v[2]=u0.z; v[3]=u0.w;
        v[4]=u1.x; v[5]=u1.y; v[6]=u1.z; v[7]=u1.w;
        i32x4 tw = pack_hi8(v);
        aout = (nl == 0) ? tw : (i32x4){0, 0, 0, 0};
    }

    // per-lane j-constants for D rows j = 4g+r (tile0) and 16+4g+r (tile1)
    float vb0[4], vw0[4], vb1[4], vw1[4];
    #pragma unroll
    for (int r = 0; r < 4; ++r) {
        const int j0 = 4 * g + r, j1 = j0 + 16;
        vb0[r] = b_ih[j0] + b_hh[j0]; vw0[r] = W_ih[j0];
        vb1[r] = b_ih[j1] + b_hh[j1]; vw1[r] = W_ih[j1];
    }
    const float bo = b_out[0];

    // ---- initial B' fragment from h0 (sigma-permuted columns, hi-only) ----
    i32x4 bh;
    {
        float v[8];
        const float* hr = h0 + (size_t)m * H;
        float4 u0 = *reinterpret_cast<const float4*>(hr + 4 * g);
        float4 u1 = *reinterpret_cast<const float4*>(hr + 16 + 4 * g);
        v[0]=u0.x; v[1]=u0.y; v[2]=u0.z; v[3]=u0.w;
        v[4]=u1.x; v[5]=u1.y; v[6]=u1.z; v[7]=u1.w;
        bh = pack_hi8(v);
    }

    const float* xr   = x + (size_t)m * T;
    float*       orow = out + (size_t)m * T;

    f32x4 d0, d1;           // tanh'd hidden state (doubles as h storage)
    float xt = xr[0];

    #pragma unroll 1
    for (int t = 0; t < T; ++t) {
        float xn = (t + 1 < T) ? xr[t + 1] : 0.0f;

        // C init: bias[j] + x[m]*W_ih[j]  (pure f32; x never rounded)
        f32x4 c0, c1;
        #pragma unroll
        for (int r = 0; r < 4; ++r) {
            c0[r] = fmaf(xt, vw0[r], vb0[r]);
            c1[r] = fmaf(xt, vw1[r], vb1[r]);
        }

        // D = (W_hi + W_lo) · h_hi^T
        c0 = mfma16(a0h, bh, c0);
        c1 = mfma16(a1h, bh, c1);
        c0 = mfma16(a0l, bh, c0);
        c1 = mfma16(a1l, bh, c1);

        // tanh in place
        #pragma unroll
        for (int r = 0; r < 4; ++r) {
            d0[r] = fast_tanh(c0[r]);
            d1[r] = fast_tanh(c1[r]);
        }

        // D -> B': per-lane hi pack in k'-order (always; o-MFMA consumes it)
        bh = (i32x4){(int)cvt_pk_bf16(d0[0], d0[1]),
                     (int)cvt_pk_bf16(d0[2], d0[3]),
                     (int)cvt_pk_bf16(d1[0], d1[1]),
                     (int)cvt_pk_bf16(d1[2], d1[3])};

        // o = W_out · h_new via MFMA row0 (off the recurrence critical path)
        f32x4 oacc = {0.0f, 0.0f, 0.0f, 0.0f};
        oacc = mfma16(aout, bh, oacc);
        if (g == 0) orow[t] = oacc[0] + bo;

        xt = xn;
    }

    // hT: h[m][j]; d0 rows j=4g..4g+3, d1 rows 16+4g..16+4g+3
    float* hb = out + (size_t)BATCH * T + (size_t)m * H;
    float4 s0, s1;
    s0.x = d0[0]; s0.y = d0[1]; s0.z = d0[2]; s0.w = d0[3];
    s1.x = d1[0]; s1.y = d1[1]; s1.z = d1[2]; s1.w = d1[3];
    *reinterpret_cast<float4*>(hb + 4 * g)      = s0;
    *reinterpret_cast<float4*>(hb + 16 + 4 * g) = s1;
}

extern "C" void kernel_launch(void* const* d_in, const int* in_sizes, int n_in,
                              void* d_out, int out_size, void* d_ws, size_t ws_size,
                              hipStream_t stream) {
    const float* x     = (const float*)d_in[0];
    const float* h0    = (const float*)d_in[1];
    const float* W_ih  = (const float*)d_in[2];
    const float* W_hh  = (const float*)d_in[3];
    const float* b_ih  = (const float*)d_in[4];
    const float* b_hh  = (const float*)d_in[5];
    const float* W_out = (const float*)d_in[6];
    const float* b_out = (const float*)d_in[7];
    float* out = (float*)d_out;

    rnn_mfma<<<BATCH / 64, 256, 0, stream>>>(
        x, h0, W_ih, W_hh, b_ih, b_hh, W_out, b_out, out);
}

// Round 13
// 24.590 us; speedup vs baseline: 1.3663x; 1.1010x over previous
//
#include <hip/hip_runtime.h>

typedef __attribute__((ext_vector_type(4))) float f32x4;
typedef __attribute__((ext_vector_type(8))) short s16x8;
typedef __attribute__((ext_vector_type(4))) int   i32x4;

constexpr int BATCH = 131072;
constexpr int T = 10;
constexpr int H = 32;

__device__ __forceinline__ unsigned cvt_pk_bf16(float a, float b) {
    unsigned d;
    asm("v_cvt_pk_bf16_f32 %0, %1, %2" : "=v"(d) : "v"(a), "v"(b));
    return d;   // lo16 = bf16(a), hi16 = bf16(b)
}

// 8 f32 (in fragment k-order) -> bf16x8 hi fragment + lo (residual) fragment
__device__ __forceinline__ void pack_hilo8(const float (&v)[8], i32x4& hi, i32x4& lo) {
    #pragma unroll
    for (int p = 0; p < 4; ++p) {
        unsigned hb = cvt_pk_bf16(v[2*p], v[2*p+1]);
        float f0 = __builtin_bit_cast(float, hb << 16);
        float f1 = __builtin_bit_cast(float, hb & 0xFFFF0000u);
        hi[p] = (int)hb;
        lo[p] = (int)cvt_pk_bf16(v[2*p] - f0, v[2*p+1] - f1);
    }
}

// hi-only pack
__device__ __forceinline__ i32x4 pack_hi8(const float (&v)[8]) {
    i32x4 hi;
    #pragma unroll
    for (int p = 0; p < 4; ++p)
        hi[p] = (int)cvt_pk_bf16(v[2*p], v[2*p+1]);
    return hi;
}

__device__ __forceinline__ f32x4 mfma16(i32x4 a, i32x4 b, f32x4 c) {
    return __builtin_amdgcn_mfma_f32_16x16x32_bf16(
        __builtin_bit_cast(s16x8, a), __builtin_bit_cast(s16x8, b), c, 0, 0, 0);
}

__device__ __forceinline__ float fast_tanh(float v) {
    // tanh(v) = 1 - 2/(exp(2v)+1); overflow-safe at both ends
    float e = __expf(2.0f * v);
    return fmaf(-2.0f, __builtin_amdgcn_rcpf(e + 1.0f), 1.0f);
}

// sigma(8g+r') = 4g+r' (r'<4), 16+4g+(r'-4) (r'>=4).
// A'[j][k'] = W_hh[j][sigma(k')], B'[k'][m] = h[m][sigma(k')].
// D-tile of step t packs directly into step t+1's B-fragment (4 cvt_pk),
// zero cross-lane ops anywhere in the loop.
// Output projection rides the MFMA pipe: aout row0 = W_out[sigma(k')].

extern "C" __global__ void __launch_bounds__(256, 4)
rnn_mfma(const float* __restrict__ x,      // [B, T]
         const float* __restrict__ h0,     // [B, H]
         const float* __restrict__ W_ih,   // [H]
         const float* __restrict__ W_hh,   // [H, H] row-major W_hh[j][k]
         const float* __restrict__ b_ih,   // [H]
         const float* __restrict__ b_hh,   // [H]
         const float* __restrict__ W_out,  // [H]
         const float* __restrict__ b_out,  // [1]
         float* __restrict__ out)          // outs [B*T] then hT [B*H]
{
    const int tid  = threadIdx.x;
    const int wave = tid >> 6;
    const int lane = tid & 63;
    const int nl   = lane & 15;            // batch slot m / D col
    const int g    = lane >> 4;
    const int base = blockIdx.x * 128 + wave * 32;   // 2 tiles x 16 rows
    const int m0   = base + nl;
    const int m1   = base + 16 + nl;

    // ---- A' fragments of W_hh (constant, sigma-permuted k') ----
    i32x4 a0h, a0l, a1h, a1l;
    {
        float v[8];
        const float* r0 = W_hh + nl * H;
        float4 u0 = *reinterpret_cast<const float4*>(r0 + 4 * g);
        float4 u1 = *reinterpret_cast<const float4*>(r0 + 16 + 4 * g);
        v[0]=u0.x; v[1]=u0.y; v[2]=u0.z; v[3]=u0.w;
        v[4]=u1.x; v[5]=u1.y; v[6]=u1.z; v[7]=u1.w;
        pack_hilo8(v, a0h, a0l);
        const float* r1 = W_hh + (nl + 16) * H;
        float4 w0 = *reinterpret_cast<const float4*>(r1 + 4 * g);
        float4 w1 = *reinterpret_cast<const float4*>(r1 + 16 + 4 * g);
        v[0]=w0.x; v[1]=w0.y; v[2]=w0.z; v[3]=w0.w;
        v[4]=w1.x; v[5]=w1.y; v[6]=w1.z; v[7]=w1.w;
        pack_hilo8(v, a1h, a1l);
    }

    // ---- aout: A row0 = W_out[sigma(k')], other rows zero ----
    i32x4 aout;
    {
        float v[8];
        float4 u0 = *reinterpret_cast<const float4*>(W_out + 4 * g);
        float4 u1 = *reinterpret_cast<const float4*>(W_out + 16 + 4 * g);
        v[0]=u0.x; v[1]=u0.y; v[2]=u0.z; v[3]=u0.w;
        v[4]=u1.x; v[5]=u1.y; v[6]=u1.z; v[7]=u1.w;
        i32x4 tw = pack_hi8(v);
        aout = (nl == 0) ? tw : (i32x4){0, 0, 0, 0};
    }

    // per-lane j-constants for D rows j = 4g+r (tile0) and 16+4g+r (tile1)
    float vb0[4], vw0[4], vb1[4], vw1[4];
    #pragma unroll
    for (int r = 0; r < 4; ++r) {
        const int j0 = 4 * g + r, j1 = j0 + 16;
        vb0[r] = b_ih[j0] + b_hh[j0]; vw0[r] = W_ih[j0];
        vb1[r] = b_ih[j1] + b_hh[j1]; vw1[r] = W_ih[j1];
    }
    const float bo = b_out[0];

    // ---- initial B' fragments from h0 (sigma-permuted columns, hi-only) ----
    i32x4 bh[2];
    #pragma unroll
    for (int u = 0; u < 2; ++u) {
        float v[8];
        const float* hr = h0 + (size_t)((u == 0) ? m0 : m1) * H;
        float4 u0 = *reinterpret_cast<const float4*>(hr + 4 * g);
        float4 u1 = *reinterpret_cast<const float4*>(hr + 16 + 4 * g);
        v[0]=u0.x; v[1]=u0.y; v[2]=u0.z; v[3]=u0.w;
        v[4]=u1.x; v[5]=u1.y; v[6]=u1.z; v[7]=u1.w;
        bh[u] = pack_hi8(v);
    }

    // ---- ALL x upfront: 5 float2 per row (rows are 40B, 8B-aligned) ----
    float xv[2][T];
    {
        const float2* p0 = reinterpret_cast<const float2*>(x + (size_t)m0 * T);
        const float2* p1 = reinterpret_cast<const float2*>(x + (size_t)m1 * T);
        #pragma unroll
        for (int i = 0; i < T / 2; ++i) {
            float2 a = p0[i]; xv[0][2*i] = a.x; xv[0][2*i+1] = a.y;
            float2 b = p1[i]; xv[1][2*i] = b.x; xv[1][2*i+1] = b.y;
        }
    }

    f32x4 d0[2], d1[2];       // tanh'd hidden state (doubles as h storage)

    #pragma unroll 1
    for (int t = 0; t < T; ++t) {
        const float xt0 = xv[0][t], xt1 = xv[1][t];

        // C init: bias[j] + x[m]*W_ih[j]  (pure f32; x never rounded)
        f32x4 c0[2], c1[2];
        #pragma unroll
        for (int r = 0; r < 4; ++r) {
            c0[0][r] = fmaf(xt0, vw0[r], vb0[r]);
            c1[0][r] = fmaf(xt0, vw1[r], vb1[r]);
            c0[1][r] = fmaf(xt1, vw0[r], vb0[r]);
            c1[1][r] = fmaf(xt1, vw1[r], vb1[r]);
        }

        // D = (W_hi + W_lo) · h_hi^T ; two independent chains interleaved
        #pragma unroll
        for (int u = 0; u < 2; ++u) { c0[u] = mfma16(a0h, bh[u], c0[u]);
                                      c1[u] = mfma16(a1h, bh[u], c1[u]); }
        #pragma unroll
        for (int u = 0; u < 2; ++u) { c0[u] = mfma16(a0l, bh[u], c0[u]);
                                      c1[u] = mfma16(a1l, bh[u], c1[u]); }

        #pragma unroll
        for (int u = 0; u < 2; ++u) {
            // tanh in place
            #pragma unroll
            for (int r = 0; r < 4; ++r) {
                d0[u][r] = fast_tanh(c0[u][r]);
                d1[u][r] = fast_tanh(c1[u][r]);
            }
            // D -> B': per-lane hi pack in k'-order
            bh[u] = (i32x4){(int)cvt_pk_bf16(d0[u][0], d0[u][1]),
                            (int)cvt_pk_bf16(d0[u][2], d0[u][3]),
                            (int)cvt_pk_bf16(d1[u][0], d1[u][1]),
                            (int)cvt_pk_bf16(d1[u][2], d1[u][3])};
            // o = W_out · h_new via MFMA row0 (off the critical path)
            f32x4 oacc = {0.0f, 0.0f, 0.0f, 0.0f};
            oacc = mfma16(aout, bh[u], oacc);
            if (g == 0) out[(size_t)(base + u * 16 + nl) * T + t] = oacc[0] + bo;
        }
    }

    // hT: h[m][j]; d0 rows j=4g..4g+3, d1 rows 16+4g..16+4g+3 per tile
    #pragma unroll
    for (int u = 0; u < 2; ++u) {
        float* hb = out + (size_t)BATCH * T + (size_t)(base + u * 16 + nl) * H;
        float4 s0, s1;
        s0.x = d0[u][0]; s0.y = d0[u][1]; s0.z = d0[u][2]; s0.w = d0[u][3];
        s1.x = d1[u][0]; s1.y = d1[u][1]; s1.z = d1[u][2]; s1.w = d1[u][3];
        *reinterpret_cast<float4*>(hb + 4 * g)      = s0;
        *reinterpret_cast<float4*>(hb + 16 + 4 * g) = s1;
    }
}

extern "C" void kernel_launch(void* const* d_in, const int* in_sizes, int n_in,
                              void* d_out, int out_size, void* d_ws, size_t ws_size,
                              hipStream_t stream) {
    const float* x     = (const float*)d_in[0];
    const float* h0    = (const float*)d_in[1];
    const float* W_ih  = (const float*)d_in[2];
    const float* W_hh  = (const float*)d_in[3];
    const float* b_ih  = (const float*)d_in[4];
    const float* b_hh  = (const float*)d_in[5];
    const float* W_out = (const float*)d_in[6];
    const float* b_out = (const float*)d_in[7];
    float* out = (float*)d_out;

    rnn_mfma<<<BATCH / 128, 256, 0, stream>>>(
        x, h0, W_ih, W_hh, b_ih, b_hh, W_out, b_out, out);
}

// Round 14
// 24.176 us; speedup vs baseline: 1.3898x; 1.0171x over previous
//
#include <hip/hip_runtime.h>

typedef __attribute__((ext_vector_type(4))) float f32x4;
typedef __attribute__((ext_vector_type(8))) short s16x8;
typedef __attribute__((ext_vector_type(4))) int   i32x4;

constexpr int BATCH = 131072;
constexpr int T = 10;
constexpr int H = 32;

__device__ __forceinline__ unsigned cvt_pk_bf16(float a, float b) {
    unsigned d;
    asm("v_cvt_pk_bf16_f32 %0, %1, %2" : "=v"(d) : "v"(a), "v"(b));
    return d;   // lo16 = bf16(a), hi16 = bf16(b)
}

// 8 f32 (in fragment k-order) -> bf16x8 hi fragment + lo (residual) fragment
__device__ __forceinline__ void pack_hilo8(const float (&v)[8], i32x4& hi, i32x4& lo) {
    #pragma unroll
    for (int p = 0; p < 4; ++p) {
        unsigned hb = cvt_pk_bf16(v[2*p], v[2*p+1]);
        float f0 = __builtin_bit_cast(float, hb << 16);
        float f1 = __builtin_bit_cast(float, hb & 0xFFFF0000u);
        hi[p] = (int)hb;
        lo[p] = (int)cvt_pk_bf16(v[2*p] - f0, v[2*p+1] - f1);
    }
}

// hi-only pack
__device__ __forceinline__ i32x4 pack_hi8(const float (&v)[8]) {
    i32x4 hi;
    #pragma unroll
    for (int p = 0; p < 4; ++p)
        hi[p] = (int)cvt_pk_bf16(v[2*p], v[2*p+1]);
    return hi;
}

__device__ __forceinline__ f32x4 mfma16(i32x4 a, i32x4 b, f32x4 c) {
    return __builtin_amdgcn_mfma_f32_16x16x32_bf16(
        __builtin_bit_cast(s16x8, a), __builtin_bit_cast(s16x8, b), c, 0, 0, 0);
}

__device__ __forceinline__ float fast_tanh(float v) {
    // tanh(v) = 1 - 2/(exp(2v)+1); overflow-safe at both ends
    float e = __expf(2.0f * v);
    return fmaf(-2.0f, __builtin_amdgcn_rcpf(e + 1.0f), 1.0f);
}

// sigma(8g+r') = 4g+r' (r'<4), 16+4g+(r'-4) (r'>=4).
// A'[j][k'] = W_hh[j][sigma(k')], B'[k'][m] = h[m][sigma(k')].
// D-tile of step t packs directly into step t+1's B-fragment (4 cvt_pk),
// zero cross-lane ops anywhere in the loop.
// Output projection rides the MFMA pipe: aout row0 = W_out[sigma(k')].
// t-loop FULLY UNROLLED: xv[] indices static -> registers (rule #20);
// safe now that no tied-operand asm remains in the body (R7/R8 lesson).

extern "C" __global__ void __launch_bounds__(256, 4)
rnn_mfma(const float* __restrict__ x,      // [B, T]
         const float* __restrict__ h0,     // [B, H]
         const float* __restrict__ W_ih,   // [H]
         const float* __restrict__ W_hh,   // [H, H] row-major W_hh[j][k]
         const float* __restrict__ b_ih,   // [H]
         const float* __restrict__ b_hh,   // [H]
         const float* __restrict__ W_out,  // [H]
         const float* __restrict__ b_out,  // [1]
         float* __restrict__ out)          // outs [B*T] then hT [B*H]
{
    const int tid  = threadIdx.x;
    const int wave = tid >> 6;
    const int lane = tid & 63;
    const int nl   = lane & 15;            // batch slot m / D col
    const int g    = lane >> 4;
    const int base = blockIdx.x * 128 + wave * 32;   // 2 tiles x 16 rows
    const int m0   = base + nl;
    const int m1   = base + 16 + nl;

    // ---- A' fragments of W_hh (constant, sigma-permuted k') ----
    i32x4 a0h, a0l, a1h, a1l;
    {
        float v[8];
        const float* r0 = W_hh + nl * H;
        float4 u0 = *reinterpret_cast<const float4*>(r0 + 4 * g);
        float4 u1 = *reinterpret_cast<const float4*>(r0 + 16 + 4 * g);
        v[0]=u0.x; v[1]=u0.y; v[2]=u0.z; v[3]=u0.w;
        v[4]=u1.x; v[5]=u1.y; v[6]=u1.z; v[7]=u1.w;
        pack_hilo8(v, a0h, a0l);
        const float* r1 = W_hh + (nl + 16) * H;
        float4 w0 = *reinterpret_cast<const float4*>(r1 + 4 * g);
        float4 w1 = *reinterpret_cast<const float4*>(r1 + 16 + 4 * g);
        v[0]=w0.x; v[1]=w0.y; v[2]=w0.z; v[3]=w0.w;
        v[4]=w1.x; v[5]=w1.y; v[6]=w1.z; v[7]=w1.w;
        pack_hilo8(v, a1h, a1l);
    }

    // ---- aout: A row0 = W_out[sigma(k')], other rows zero ----
    i32x4 aout;
    {
        float v[8];
        float4 u0 = *reinterpret_cast<const float4*>(W_out + 4 * g);
        float4 u1 = *reinterpret_cast<const float4*>(W_out + 16 + 4 * g);
        v[0]=u0.x; v[1]=u0.y; v[2]=u0.z; v[3]=u0.w;
        v[4]=u1.x; v[5]=u1.y; v[6]=u1.z; v[7]=u1.w;
        i32x4 tw = pack_hi8(v);
        aout = (nl == 0) ? tw : (i32x4){0, 0, 0, 0};
    }

    // per-lane j-constants for D rows j = 4g+r (tile0) and 16+4g+r (tile1)
    float vb0[4], vw0[4], vb1[4], vw1[4];
    #pragma unroll
    for (int r = 0; r < 4; ++r) {
        const int j0 = 4 * g + r, j1 = j0 + 16;
        vb0[r] = b_ih[j0] + b_hh[j0]; vw0[r] = W_ih[j0];
        vb1[r] = b_ih[j1] + b_hh[j1]; vw1[r] = W_ih[j1];
    }
    const float bo = b_out[0];

    // ---- initial B' fragments from h0 (sigma-permuted columns, hi-only) ----
    i32x4 bh[2];
    #pragma unroll
    for (int u = 0; u < 2; ++u) {
        float v[8];
        const float* hr = h0 + (size_t)((u == 0) ? m0 : m1) * H;
        float4 u0 = *reinterpret_cast<const float4*>(hr + 4 * g);
        float4 u1 = *reinterpret_cast<const float4*>(hr + 16 + 4 * g);
        v[0]=u0.x; v[1]=u0.y; v[2]=u0.z; v[3]=u0.w;
        v[4]=u1.x; v[5]=u1.y; v[6]=u1.z; v[7]=u1.w;
        bh[u] = pack_hi8(v);
    }

    // ---- ALL x upfront: 5 float2 per row (rows are 40B, 8B-aligned) ----
    float xv[2][T];
    {
        const float2* p0 = reinterpret_cast<const float2*>(x + (size_t)m0 * T);
        const float2* p1 = reinterpret_cast<const float2*>(x + (size_t)m1 * T);
        #pragma unroll
        for (int i = 0; i < T / 2; ++i) {
            float2 a = p0[i]; xv[0][2*i] = a.x; xv[0][2*i+1] = a.y;
            float2 b = p1[i]; xv[1][2*i] = b.x; xv[1][2*i+1] = b.y;
        }
    }

    f32x4 d0[2], d1[2];       // tanh'd hidden state (doubles as h storage)

    #pragma unroll
    for (int t = 0; t < T; ++t) {
        const float xt0 = xv[0][t], xt1 = xv[1][t];

        // C init: bias[j] + x[m]*W_ih[j]  (pure f32; x never rounded)
        f32x4 c0[2], c1[2];
        #pragma unroll
        for (int r = 0; r < 4; ++r) {
            c0[0][r] = fmaf(xt0, vw0[r], vb0[r]);
            c1[0][r] = fmaf(xt0, vw1[r], vb1[r]);
            c0[1][r] = fmaf(xt1, vw0[r], vb0[r]);
            c1[1][r] = fmaf(xt1, vw1[r], vb1[r]);
        }

        // D = (W_hi + W_lo) · h_hi^T ; two independent chains interleaved
        #pragma unroll
        for (int u = 0; u < 2; ++u) { c0[u] = mfma16(a0h, bh[u], c0[u]);
                                      c1[u] = mfma16(a1h, bh[u], c1[u]); }
        #pragma unroll
        for (int u = 0; u < 2; ++u) { c0[u] = mfma16(a0l, bh[u], c0[u]);
                                      c1[u] = mfma16(a1l, bh[u], c1[u]); }

        #pragma unroll
        for (int u = 0; u < 2; ++u) {
            // tanh in place
            #pragma unroll
            for (int r = 0; r < 4; ++r) {
                d0[u][r] = fast_tanh(c0[u][r]);
                d1[u][r] = fast_tanh(c1[u][r]);
            }
            // D -> B': per-lane hi pack in k'-order
            bh[u] = (i32x4){(int)cvt_pk_bf16(d0[u][0], d0[u][1]),
                            (int)cvt_pk_bf16(d0[u][2], d0[u][3]),
                            (int)cvt_pk_bf16(d1[u][0], d1[u][1]),
                            (int)cvt_pk_bf16(d1[u][2], d1[u][3])};
            // o = W_out · h_new via MFMA row0 (off the critical path)
            f32x4 oacc = {0.0f, 0.0f, 0.0f, 0.0f};
            oacc = mfma16(aout, bh[u], oacc);
            if (g == 0) out[(size_t)(base + u * 16 + nl) * T + t] = oacc[0] + bo;
        }
    }

    // hT: h[m][j]; d0 rows j=4g..4g+3, d1 rows 16+4g..16+4g+3 per tile
    #pragma unroll
    for (int u = 0; u < 2; ++u) {
        float* hb = out + (size_t)BATCH * T + (size_t)(base + u * 16 + nl) * H;
        float4 s0, s1;
        s0.x = d0[u][0]; s0.y = d0[u][1]; s0.z = d0[u][2]; s0.w = d0[u][3];
        s1.x = d1[u][0]; s1.y = d1[u][1]; s1.z = d1[u][2]; s1.w = d1[u][3];
        *reinterpret_cast<float4*>(hb + 4 * g)      = s0;
        *reinterpret_cast<float4*>(hb + 16 + 4 * g) = s1;
    }
}

extern "C" void kernel_launch(void* const* d_in, const int* in_sizes, int n_in,
                              void* d_out, int out_size, void* d_ws, size_t ws_size,
                              hipStream_t stream) {
    const float* x     = (const float*)d_in[0];
    const float* h0    = (const float*)d_in[1];
    const float* W_ih  = (const float*)d_in[2];
    const float* W_hh  = (const float*)d_in[3];
    const float* b_ih  = (const float*)d_in[4];
    const float* b_hh  = (const float*)d_in[5];
    const float* W_out = (const float*)d_in[6];
    const float* b_out = (const float*)d_in[7];
    float* out = (float*)d_out;

    rnn_mfma<<<BATCH / 128, 256, 0, stream>>>(
        x, h0, W_ih, W_hh, b_ih, b_hh, W_out, b_out, out);
}